// Round 1
// baseline (238.120 us; speedup 1.0000x reference)
//
#include <hip/hip_runtime.h>

#define NSEG 8
#define LSEG 32768
#define NCH 128
#define EPS_GN 1e-5f
#define KSCALE 0.005524271728019903f   // 1/sqrt(32768)
#define QSCALE 0.17677669529663687f    // 1/sqrt(32)

typedef __attribute__((ext_vector_type(4))) float f32x4;
typedef __attribute__((ext_vector_type(8))) __bf16 bf16x8;
typedef __attribute__((ext_vector_type(4))) short s16x4;

static __device__ __forceinline__ unsigned short f2bf(float f) {
  unsigned int u = __float_as_uint(f);
  u += 0x7fffu + ((u >> 16) & 1u);
  return (unsigned short)(u >> 16);
}
static __device__ __forceinline__ float bf2f(unsigned short s) {
  return __uint_as_float(((unsigned int)s) << 16);
}

// ---- W_qkv fp32 [128][384] -> WT bf16 [384][128] (transposed for B-frags)
__global__ void k_wcvt(const float* __restrict__ W, unsigned short* __restrict__ WT) {
  int idx = blockIdx.x * 256 + threadIdx.x;   // 49152 total
  int n = idx >> 7, k = idx & 127;
  WT[idx] = f2bf(W[k * 384 + n]);
}

// ---- per-block partial sum/sumsq of x (GN1 stats)
__global__ __launch_bounds__(256) void k_stats1(const float* __restrict__ x, float* __restrict__ part) {
  int t = threadIdx.x;
  int b = blockIdx.x >> 6, p = blockIdx.x & 63;
  const float4* xp = (const float4*)x + (size_t)b * 1048576 + (size_t)p * 16384;
  float s = 0.f, q = 0.f;
  for (int i = 0; i < 64; ++i) {
    float4 v = xp[t + i * 256];
    s += v.x + v.y + v.z + v.w;
    q += v.x*v.x + v.y*v.y + v.z*v.z + v.w*v.w;
  }
  #pragma unroll
  for (int o = 1; o < 64; o <<= 1) { s += __shfl_xor(s, o); q += __shfl_xor(q, o); }
  __shared__ float red[8];
  int wave = t >> 6, lane = t & 63;
  if (lane == 0) { red[wave*2] = s; red[wave*2+1] = q; }
  __syncthreads();
  if (t == 0) {
    part[blockIdx.x*2]   = red[0] + red[2] + red[4] + red[6];
    part[blockIdx.x*2+1] = red[1] + red[3] + red[5] + red[7];
  }
}

__global__ void k_stats1_final(const float* __restrict__ part, float* __restrict__ stats) {
  int b = blockIdx.x, t = threadIdx.x;  // 64 threads
  float s = part[(b*64 + t)*2], q = part[(b*64 + t)*2 + 1];
  #pragma unroll
  for (int o = 1; o < 64; o <<= 1) { s += __shfl_xor(s, o); q += __shfl_xor(q, o); }
  if (t == 0) {
    const float invN = 1.f / 4194304.f;
    float mu = s * invN;
    float var = q * invN - mu * mu;
    stats[b*2] = mu;
    stats[b*2+1] = rsqrtf(var + EPS_GN);
  }
}

// ---- fused: GN1-normalize -> qkv MFMA -> store q(frag layout,bf16); exp(k)->sum_e, ctx += E^T@V
__global__ __launch_bounds__(512) void k_qkv(
    const float* __restrict__ x, const float* __restrict__ gn1w, const float* __restrict__ gn1b,
    const float* __restrict__ stats1, const unsigned short* __restrict__ WT,
    unsigned short* __restrict__ q_ws, float* __restrict__ sume_p, float* __restrict__ ctx_p)
{
  __shared__ __attribute__((aligned(16))) unsigned short sW[384 * 136];  // 104448 B
  __shared__ __attribute__((aligned(16))) unsigned short sA[128 * 136];  //  34816 B
  __shared__ float sume_lds[8 * 128];                                    //   4096 B

  const int t = threadIdx.x;
  const int wave = t >> 6, lane = t & 63;
  const int b = blockIdx.x >> 5, sub = blockIdx.x & 31;
  const int lm = lane & 15, lg = lane >> 4;

  const ushort4* wt4 = (const ushort4*)WT;
  #pragma unroll
  for (int i = 0; i < 24; ++i) {
    int f = t + i * 512;                       // 12288 ushort4 total
    *(ushort4*)&sW[(f >> 5) * 136 + (f & 31) * 4] = wt4[f];
  }

  const float mu = stats1[b*2], rs = stats1[b*2+1];
  const int c4 = t & 31;
  const float4 w4 = *(const float4*)&gn1w[c4*4];
  const float4 g4 = *(const float4*)&gn1b[c4*4];

  f32x4 ctx[4][2][2];
  #pragma unroll
  for (int h = 0; h < 4; ++h)
    #pragma unroll
    for (int i = 0; i < 2; ++i)
      #pragma unroll
      for (int j = 0; j < 2; ++j) ctx[h][i][j] = (f32x4){0.f,0.f,0.f,0.f};
  float se[8] = {0.f,0.f,0.f,0.f,0.f,0.f,0.f,0.f};

  const float4* xp = (const float4*)x + ((size_t)b * LSEG + (size_t)sub * 1024) * 32;
  ushort4* q4 = (ushort4*)q_ws;

  for (int ch = 0; ch < 8; ++ch) {
    // stage normalized bf16 A-tile (128 rows x 128 k), pitch 136 to dodge bank conflicts
    #pragma unroll
    for (int i = 0; i < 8; ++i) {
      int f = t + i * 512;
      int row = f >> 5;
      float4 v = xp[ch * 4096 + f];
      float4 nv;
      nv.x = (v.x - mu) * rs * w4.x + g4.x;
      nv.y = (v.y - mu) * rs * w4.y + g4.y;
      nv.z = (v.z - mu) * rs * w4.z + g4.z;
      nv.w = (v.w - mu) * rs * w4.w + g4.w;
      *(ushort4*)&sA[row * 136 + c4 * 4] = make_ushort4(f2bf(nv.x), f2bf(nv.y), f2bf(nv.z), f2bf(nv.w));
    }
    __syncthreads();

    const int arow = wave * 16 + lm;
    bf16x8 af[4];
    #pragma unroll
    for (int kk = 0; kk < 4; ++kk)
      af[kk] = *(const bf16x8*)&sA[arow * 136 + kk * 32 + lg * 8];

    // q tiles 0..7
    f32x4 qa[8];
    #pragma unroll
    for (int nt = 0; nt < 8; ++nt) qa[nt] = (f32x4){0.f,0.f,0.f,0.f};
    #pragma unroll
    for (int kk = 0; kk < 4; ++kk)
      #pragma unroll
      for (int nt = 0; nt < 8; ++nt) {
        bf16x8 bf = *(const bf16x8*)&sW[(nt * 16 + lm) * 136 + kk * 32 + lg * 8];
        qa[nt] = __builtin_amdgcn_mfma_f32_16x16x32_bf16(af[kk], bf, qa[nt], 0, 0, 0);
      }
    const size_t qbase = (((size_t)blockIdx.x * 8 + ch) * 8 + wave) * 8;
    #pragma unroll
    for (int nt = 0; nt < 8; ++nt)
      q4[(qbase + nt) * 64 + lane] =
          make_ushort4(f2bf(qa[nt][0]), f2bf(qa[nt][1]), f2bf(qa[nt][2]), f2bf(qa[nt][3]));

    // k tiles 8..15, v tiles 16..23
    f32x4 ka[8], va[8];
    #pragma unroll
    for (int j = 0; j < 8; ++j) { ka[j] = (f32x4){0.f,0.f,0.f,0.f}; va[j] = (f32x4){0.f,0.f,0.f,0.f}; }
    #pragma unroll
    for (int kk = 0; kk < 4; ++kk) {
      #pragma unroll
      for (int j = 0; j < 8; ++j) {
        bf16x8 bk = *(const bf16x8*)&sW[((8 + j) * 16 + lm) * 136 + kk * 32 + lg * 8];
        ka[j] = __builtin_amdgcn_mfma_f32_16x16x32_bf16(af[kk], bk, ka[j], 0, 0, 0);
      }
      #pragma unroll
      for (int j = 0; j < 8; ++j) {
        bf16x8 bv = *(const bf16x8*)&sW[((16 + j) * 16 + lm) * 136 + kk * 32 + lg * 8];
        va[j] = __builtin_amdgcn_mfma_f32_16x16x32_bf16(af[kk], bv, va[j], 0, 0, 0);
      }
    }
    // e = exp(k*scale); per-column running sum; ctx += E^T @ V via frag-layout identity
    #pragma unroll
    for (int j = 0; j < 8; ++j) {
      #pragma unroll
      for (int r = 0; r < 4; ++r) ka[j][r] = __expf(ka[j][r] * KSCALE);
      float s = ka[j][0] + ka[j][1] + ka[j][2] + ka[j][3];
      s += __shfl_xor(s, 16);
      s += __shfl_xor(s, 32);
      se[j] += s;
    }
    #pragma unroll
    for (int h = 0; h < 4; ++h) {
      s16x4 aE[2], bV[2];
      #pragma unroll
      for (int d = 0; d < 2; ++d) {
        #pragma unroll
        for (int r = 0; r < 4; ++r) {
          aE[d][r] = (short)f2bf(ka[2*h + d][r]);
          bV[d][r] = (short)f2bf(va[2*h + d][r]);
        }
      }
      #pragma unroll
      for (int dt = 0; dt < 2; ++dt)
        #pragma unroll
        for (int vt = 0; vt < 2; ++vt)
          ctx[h][dt][vt] = __builtin_amdgcn_mfma_f32_16x16x16bf16_1k(aE[dt], bV[vt], ctx[h][dt][vt], 0, 0, 0);
    }
    __syncthreads();
  }

  // block reduce sum_e
  if (lane < 16) {
    #pragma unroll
    for (int j = 0; j < 8; ++j) sume_lds[wave * 128 + j * 16 + lane] = se[j];
  }
  __syncthreads();
  if (t < 128) {
    float s = 0.f;
    #pragma unroll
    for (int w = 0; w < 8; ++w) s += sume_lds[w * 128 + t];
    sume_p[(size_t)blockIdx.x * 128 + t] = s;
  }
  // block reduce ctx (deterministic wave-by-wave; reuse sA as float buffer)
  float* cbuf = (float*)sA;
  for (int w = 0; w < 8; ++w) {
    if (wave == w) {
      #pragma unroll
      for (int h = 0; h < 4; ++h)
        #pragma unroll
        for (int dt = 0; dt < 2; ++dt)
          #pragma unroll
          for (int vt = 0; vt < 2; ++vt)
            #pragma unroll
            for (int r = 0; r < 4; ++r) {
              int idx = (h * 32 + dt * 16 + lg * 4 + r) * 32 + vt * 16 + lm;
              if (w == 0) cbuf[idx] = ctx[h][dt][vt][r];
              else        cbuf[idx] += ctx[h][dt][vt][r];
            }
    }
    __syncthreads();
  }
  #pragma unroll
  for (int i = 0; i < 8; ++i) {
    int f = t + i * 512;
    ctx_p[(size_t)blockIdx.x * 4096 + f] = cbuf[f];
  }
}

// ---- finalize: reduce partials, normalize context, fold Wc = blockdiag(ctx) @ W_out (store transposed bf16)
__global__ __launch_bounds__(512) void k_ctx_final(
    const float* __restrict__ sume_p, const float* __restrict__ ctx_p,
    const float* __restrict__ Wout, unsigned short* __restrict__ WcT)
{
  __shared__ float sse[128];
  __shared__ float sctx[4096];
  __shared__ float sWo[16384];
  const int t = threadIdx.x, b = blockIdx.x;
  if (t < 128) {
    float s = 0.f;
    for (int blk = 0; blk < 32; ++blk) s += sume_p[(size_t)(b * 32 + blk) * 128 + t];
    sse[t] = s;
  }
  float cv[8];
  #pragma unroll
  for (int j = 0; j < 8; ++j) {
    int idx = t + j * 512;
    float s = 0.f;
    for (int blk = 0; blk < 32; ++blk) s += ctx_p[(size_t)(b * 32 + blk) * 4096 + idx];
    cv[j] = s;
  }
  #pragma unroll
  for (int j = 0; j < 32; ++j) sWo[t + j * 512] = Wout[t + j * 512];
  __syncthreads();
  #pragma unroll
  for (int j = 0; j < 8; ++j) {
    int idx = t + j * 512;
    sctx[idx] = cv[j] / sse[idx >> 5];
  }
  __syncthreads();
  const int p = t >> 2, c0 = (t & 3) * 32;
  const int h = p >> 5;
  float acc[32];
  #pragma unroll
  for (int j = 0; j < 32; ++j) acc[j] = 0.f;
  for (int v = 0; v < 32; ++v) {
    float a = sctx[p * 32 + v];
    const float* wr = &sWo[(h * 32 + v) * 128 + c0];
    #pragma unroll
    for (int j = 0; j < 32; ++j) acc[j] += a * wr[j];
  }
  #pragma unroll
  for (int j = 0; j < 32; ++j)
    WcT[((size_t)b * 128 + (c0 + j)) * 128 + p] = f2bf(acc[j]);
}

// ---- q-softmax -> out = q_soft @ Wc (MFMA) -> GN2 partial stats; out overwrites q buffer (linear bf16)
__global__ __launch_bounds__(512) void k_out(
    unsigned short* __restrict__ q_ws, const unsigned short* __restrict__ WcT,
    float* __restrict__ stats2_p)
{
  __shared__ __attribute__((aligned(16))) unsigned short sQ[128 * 136];
  __shared__ __attribute__((aligned(16))) unsigned short sWc[128 * 136];
  __shared__ __attribute__((aligned(16))) unsigned short sO[128 * 136];
  __shared__ float red[16];

  const int t = threadIdx.x;
  const int wave = t >> 6, lane = t & 63;
  const int b = blockIdx.x >> 5, sub = blockIdx.x & 31;
  const int lm = lane & 15, lg = lane >> 4;

  const ushort4* wc4 = (const ushort4*)WcT + (size_t)b * 4096;
  #pragma unroll
  for (int i = 0; i < 8; ++i) {
    int f = t + i * 512;
    *(ushort4*)&sWc[(f >> 5) * 136 + (f & 31) * 4] = wc4[f];
  }

  ushort4* q4 = (ushort4*)q_ws;
  float ssum = 0.f, ssq = 0.f;

  for (int ch = 0; ch < 8; ++ch) {
    const size_t qbase = (((size_t)blockIdx.x * 8 + ch) * 8 + wave) * 8;
    ushort4 qf[8];
    #pragma unroll
    for (int nt = 0; nt < 8; ++nt) qf[nt] = q4[(qbase + nt) * 64 + lane];
    const int rbase = wave * 16 + lg * 4;
    #pragma unroll
    for (int h = 0; h < 4; ++h) {
      float a0[4], a1[4], m[4], e0[4], e1[4], sm[4];
      a0[0] = bf2f(qf[2*h].x) * QSCALE;   a0[1] = bf2f(qf[2*h].y) * QSCALE;
      a0[2] = bf2f(qf[2*h].z) * QSCALE;   a0[3] = bf2f(qf[2*h].w) * QSCALE;
      a1[0] = bf2f(qf[2*h+1].x) * QSCALE; a1[1] = bf2f(qf[2*h+1].y) * QSCALE;
      a1[2] = bf2f(qf[2*h+1].z) * QSCALE; a1[3] = bf2f(qf[2*h+1].w) * QSCALE;
      #pragma unroll
      for (int r = 0; r < 4; ++r) m[r] = fmaxf(a0[r], a1[r]);
      #pragma unroll
      for (int o = 1; o < 16; o <<= 1)
        #pragma unroll
        for (int r = 0; r < 4; ++r) m[r] = fmaxf(m[r], __shfl_xor(m[r], o));
      #pragma unroll
      for (int r = 0; r < 4; ++r) {
        e0[r] = __expf(a0[r] - m[r]); e1[r] = __expf(a1[r] - m[r]); sm[r] = e0[r] + e1[r];
      }
      #pragma unroll
      for (int o = 1; o < 16; o <<= 1)
        #pragma unroll
        for (int r = 0; r < 4; ++r) sm[r] += __shfl_xor(sm[r], o);
      #pragma unroll
      for (int r = 0; r < 4; ++r) {
        float inv = 1.f / sm[r];
        sQ[(rbase + r) * 136 + h * 32 + lm]      = f2bf(e0[r] * inv);
        sQ[(rbase + r) * 136 + h * 32 + 16 + lm] = f2bf(e1[r] * inv);
      }
    }
    __syncthreads();
    const int arow = wave * 16 + lm;
    bf16x8 af[4];
    #pragma unroll
    for (int kk = 0; kk < 4; ++kk)
      af[kk] = *(const bf16x8*)&sQ[arow * 136 + kk * 32 + lg * 8];
    f32x4 acc[8];
    #pragma unroll
    for (int nt = 0; nt < 8; ++nt) acc[nt] = (f32x4){0.f,0.f,0.f,0.f};
    #pragma unroll
    for (int kk = 0; kk < 4; ++kk)
      #pragma unroll
      for (int nt = 0; nt < 8; ++nt) {
        bf16x8 bf = *(const bf16x8*)&sWc[(nt * 16 + lm) * 136 + kk * 32 + lg * 8];
        acc[nt] = __builtin_amdgcn_mfma_f32_16x16x32_bf16(af[kk], bf, acc[nt], 0, 0, 0);
      }
    #pragma unroll
    for (int nt = 0; nt < 8; ++nt)
      #pragma unroll
      for (int r = 0; r < 4; ++r) {
        float v = acc[nt][r];
        ssum += v; ssq += v * v;
        sO[(rbase + r) * 136 + nt * 16 + lm] = f2bf(v);
      }
    __syncthreads();
    const size_t rowg = (size_t)b * LSEG + (size_t)sub * 1024 + (size_t)ch * 128;
    #pragma unroll
    for (int i = 0; i < 8; ++i) {
      int f = t + i * 512;
      q4[(rowg + (f >> 5)) * 32 + (f & 31)] = *(const ushort4*)&sO[(f >> 5) * 136 + (f & 31) * 4];
    }
  }
  #pragma unroll
  for (int o = 1; o < 64; o <<= 1) { ssum += __shfl_xor(ssum, o); ssq += __shfl_xor(ssq, o); }
  if (lane == 0) { red[wave*2] = ssum; red[wave*2+1] = ssq; }
  __syncthreads();
  if (t == 0) {
    float s = 0.f, q = 0.f;
    #pragma unroll
    for (int w = 0; w < 8; ++w) { s += red[w*2]; q += red[w*2+1]; }
    stats2_p[blockIdx.x*2] = s; stats2_p[blockIdx.x*2+1] = q;
  }
}

__global__ void k_stats2_final(const float* __restrict__ part, float* __restrict__ stats) {
  int b = blockIdx.x, t = threadIdx.x;  // 32 threads
  float s = part[(b*32 + t)*2], q = part[(b*32 + t)*2 + 1];
  #pragma unroll
  for (int o = 1; o < 32; o <<= 1) { s += __shfl_xor(s, o); q += __shfl_xor(q, o); }
  if (t == 0) {
    const float invN = 1.f / 4194304.f;
    float mu = s * invN;
    float var = q * invN - mu * mu;
    stats[b*2] = mu;
    stats[b*2+1] = rsqrtf(var + EPS_GN);
  }
}

// ---- GN2 + residual
__global__ __launch_bounds__(256) void k_final(
    const float* __restrict__ x, const unsigned short* __restrict__ out_ws,
    const float* __restrict__ stats2, const float* __restrict__ gn2w, const float* __restrict__ gn2b,
    float* __restrict__ y)
{
  const int t = threadIdx.x;
  const int b = blockIdx.x >> 8, blk = blockIdx.x & 255;
  const float mu = stats2[b*2], rs = stats2[b*2+1];
  const int c4 = t & 31;
  const float4 w4 = *(const float4*)&gn2w[c4*4];
  const float4 g4 = *(const float4*)&gn2b[c4*4];
  const size_t base = (size_t)b * 1048576 + (size_t)blk * 4096;
  const float4* xp = (const float4*)x + base;
  const ushort4* op = (const ushort4*)out_ws + base;
  float4* yp = (float4*)y + base;
  #pragma unroll
  for (int i = 0; i < 16; ++i) {
    int f = t + i * 256;
    float4 xv = xp[f];
    ushort4 ov = op[f];
    float4 r;
    r.x = (bf2f(ov.x) - mu) * rs * w4.x + g4.x + xv.x;
    r.y = (bf2f(ov.y) - mu) * rs * w4.y + g4.y + xv.y;
    r.z = (bf2f(ov.z) - mu) * rs * w4.z + g4.z + xv.z;
    r.w = (bf2f(ov.w) - mu) * rs * w4.w + g4.w + xv.w;
    yp[f] = r;
  }
}

extern "C" void kernel_launch(void* const* d_in, const int* in_sizes, int n_in,
                              void* d_out, int out_size, void* d_ws, size_t ws_size,
                              hipStream_t stream) {
  const float* x    = (const float*)d_in[0];
  const float* gn1w = (const float*)d_in[1];
  const float* gn1b = (const float*)d_in[2];
  const float* Wqkv = (const float*)d_in[3];
  const float* Wout = (const float*)d_in[4];
  const float* gn2w = (const float*)d_in[5];
  const float* gn2b = (const float*)d_in[6];
  float* y = (float*)d_out;
  char* ws = (char*)d_ws;

  float*          stats1p = (float*)(ws + 0);            // 512*2 f32
  float*          stats1  = (float*)(ws + 4096);         // 16 f32
  unsigned short* WT      = (unsigned short*)(ws + 8192);   // 384*128 bf16 = 98304B
  float*          sume_p  = (float*)(ws + 106496);       // 256*128 f32 = 131072B
  float*          ctx_p   = (float*)(ws + 237568);       // 256*4096 f32 = 4194304B
  unsigned short* WcT     = (unsigned short*)(ws + 4431872); // 8*128*128 bf16 = 262144B
  float*          stats2p = (float*)(ws + 4694016);      // 256*2 f32
  float*          stats2  = (float*)(ws + 4696064);      // 16 f32
  unsigned short* q_ws    = (unsigned short*)(ws + 4718592); // 8*32768*128 bf16 = 67108864B

  hipLaunchKernelGGL(k_wcvt,         dim3(192),  dim3(256), 0, stream, Wqkv, WT);
  hipLaunchKernelGGL(k_stats1,       dim3(512),  dim3(256), 0, stream, x, stats1p);
  hipLaunchKernelGGL(k_stats1_final, dim3(8),    dim3(64),  0, stream, stats1p, stats1);
  hipLaunchKernelGGL(k_qkv,          dim3(256),  dim3(512), 0, stream, x, gn1w, gn1b, stats1, WT, q_ws, sume_p, ctx_p);
  hipLaunchKernelGGL(k_ctx_final,    dim3(8),    dim3(512), 0, stream, sume_p, ctx_p, Wout, WcT);
  hipLaunchKernelGGL(k_out,          dim3(256),  dim3(512), 0, stream, q_ws, WcT, stats2p);
  hipLaunchKernelGGL(k_stats2_final, dim3(8),    dim3(32),  0, stream, stats2p, stats2);
  hipLaunchKernelGGL(k_final,        dim3(2048), dim3(256), 0, stream, x, q_ws, stats2, gn2w, gn2b, y);
}

// Round 2
// 214.002 us; speedup vs baseline: 1.1127x; 1.1127x over previous
//
#include <hip/hip_runtime.h>

#define NSEG 8
#define LSEG 32768
#define EPS_GN 1e-5f
#define KSCALE 0.005524271728019903f   // 1/sqrt(32768)
#define QSCALE 0.17677669529663687f    // 1/sqrt(32)

typedef __attribute__((ext_vector_type(4))) float f32x4;
typedef __attribute__((ext_vector_type(8))) __bf16 bf16x8;
typedef __attribute__((ext_vector_type(4))) short s16x4;

static __device__ __forceinline__ unsigned short f2bf(float f) {
  unsigned int u = __float_as_uint(f);
  u += 0x7fffu + ((u >> 16) & 1u);
  return (unsigned short)(u >> 16);
}
static __device__ __forceinline__ float bf2f(unsigned short s) {
  return __uint_as_float(((unsigned int)s) << 16);
}
static __device__ __forceinline__ bf16x8 cvt8(float4 a, float4 b) {
  bf16x8 r;
  r[0] = (__bf16)a.x; r[1] = (__bf16)a.y; r[2] = (__bf16)a.z; r[3] = (__bf16)a.w;
  r[4] = (__bf16)b.x; r[5] = (__bf16)b.y; r[6] = (__bf16)b.z; r[7] = (__bf16)b.w;
  return r;
}
static __device__ __forceinline__ s16x4 pack4(float a, float b, float c, float d) {
  union { __bf16 h[4]; s16x4 s; } u;
  u.h[0] = (__bf16)a; u.h[1] = (__bf16)b; u.h[2] = (__bf16)c; u.h[3] = (__bf16)d;
  return u.s;
}
static __device__ __forceinline__ ushort4 packu4(f32x4 v) {
  union { __bf16 h[4]; ushort4 u; } u;
  u.h[0] = (__bf16)v[0]; u.h[1] = (__bf16)v[1]; u.h[2] = (__bf16)v[2]; u.h[3] = (__bf16)v[3];
  return u.u;
}

// ---- W_qkv fp32 [128][384] -> WT bf16 [384][128], gn1w folded into channels
__global__ void k_wcvt(const float* __restrict__ W, const float* __restrict__ gn1w,
                       unsigned short* __restrict__ WT) {
  int idx = blockIdx.x * 256 + threadIdx.x;   // 49152 total
  int n = idx >> 7, ch = idx & 127;
  WT[idx] = f2bf(gn1w[ch] * W[ch * 384 + n]);
}

// ---- per-block partial sum/sumsq of x (GN1 stats)
__global__ __launch_bounds__(256) void k_stats1(const float* __restrict__ x, float* __restrict__ part) {
  int t = threadIdx.x;
  int b = blockIdx.x >> 6, p = blockIdx.x & 63;
  const float4* xp = (const float4*)x + (size_t)b * 1048576 + (size_t)p * 16384;
  float s = 0.f, q = 0.f;
  for (int i = 0; i < 64; ++i) {
    float4 v = xp[t + i * 256];
    s += v.x + v.y + v.z + v.w;
    q += v.x*v.x + v.y*v.y + v.z*v.z + v.w*v.w;
  }
  #pragma unroll
  for (int o = 1; o < 64; o <<= 1) { s += __shfl_xor(s, o); q += __shfl_xor(q, o); }
  __shared__ float red[8];
  int wave = t >> 6, lane = t & 63;
  if (lane == 0) { red[wave*2] = s; red[wave*2+1] = q; }
  __syncthreads();
  if (t == 0) {
    part[blockIdx.x*2]   = red[0] + red[2] + red[4] + red[6];
    part[blockIdx.x*2+1] = red[1] + red[3] + red[5] + red[7];
  }
}

__global__ void k_stats1_final(const float* __restrict__ part, float* __restrict__ stats) {
  int b = blockIdx.x, t = threadIdx.x;  // 64 threads
  float s = part[(b*64 + t)*2], q = part[(b*64 + t)*2 + 1];
  #pragma unroll
  for (int o = 1; o < 64; o <<= 1) { s += __shfl_xor(s, o); q += __shfl_xor(q, o); }
  if (t == 0) {
    const float invN = 1.f / 4194304.f;
    float mu = s * invN;
    float var = q * invN - mu * mu;
    stats[b*2] = mu;
    stats[b*2+1] = rsqrtf(var + EPS_GN);
  }
}

// ---- per-segment folded GN1 bias through W_qkv: cb[n] = (b - mu*rs*w) @ W[:,n]
__global__ void k_bias(const float* __restrict__ Wqkv, const float* __restrict__ gn1w,
                       const float* __restrict__ gn1b, const float* __restrict__ stats1,
                       float* __restrict__ biasv, float* __restrict__ alpha) {
  int seg = blockIdx.x, n = threadIdx.x;  // 384 threads
  float mu = stats1[seg*2], rs = stats1[seg*2+1];
  float s = 0.f;
  for (int ch = 0; ch < 128; ++ch)
    s += (gn1b[ch] - mu * rs * gn1w[ch]) * Wqkv[ch * 384 + n];
  float scale = (n < 128) ? QSCALE : ((n < 256) ? KSCALE : 1.f);
  biasv[seg*384 + n] = s * scale;
  if (n == 0) {
    alpha[seg*4]   = rs * QSCALE;
    alpha[seg*4+1] = rs * KSCALE;
    alpha[seg*4+2] = rs;
  }
}

// ---- fused GEMM: x(bf16 frags direct from global) @ W(register-resident frags)
// q stored TRANSPOSED (y^T tiles, raw, rs/cb deferred); k->exp->sum; ctx += E^T@V
__global__ __launch_bounds__(512, 2) void k_qkv(
    const float* __restrict__ x, const unsigned short* __restrict__ WT,
    const float* __restrict__ biasv, const float* __restrict__ alpha,
    unsigned short* __restrict__ q_ws, float* __restrict__ sume_p, float* __restrict__ ctx_p)
{
  __shared__ float cbuf[4096];       // 16 KB: ctx reduce
  __shared__ float sume_lds[256];

  const int t = threadIdx.x;
  const int wave = t >> 6, lane = t & 63;
  const int rg = wave >> 2, h = wave & 3;
  const int lm = lane & 15, lg = lane >> 4;
  const int bid = blockIdx.x;               // 256 = 8 seg * 32 sub
  const int seg = bid >> 5, sub = bid & 31;

  // register-resident W fragments [nt][kk] (dual-use A/B layout)
  bf16x8 wq[2][4], wk[2][4], wv[2][4];
  #pragma unroll
  for (int nt = 0; nt < 2; ++nt)
    #pragma unroll
    for (int kk = 0; kk < 4; ++kk) {
      int row = h*32 + nt*16 + lm;
      wq[nt][kk] = *(const bf16x8*)&WT[(row      ) * 128 + kk*32 + lg*8];
      wk[nt][kk] = *(const bf16x8*)&WT[(row + 128) * 128 + kk*32 + lg*8];
      wv[nt][kk] = *(const bf16x8*)&WT[(row + 256) * 128 + kk*32 + lg*8];
    }
  const float alk = alpha[seg*4 + 1];
  const float alv = alpha[seg*4 + 2];
  float ckv[2], cvv[2];
  #pragma unroll
  for (int nt = 0; nt < 2; ++nt) {
    ckv[nt] = biasv[seg*384 + 128 + h*32 + nt*16 + lm];
    cvv[nt] = biasv[seg*384 + 256 + h*32 + nt*16 + lm];
  }

  f32x4 ctx00 = {0,0,0,0}, ctx01 = {0,0,0,0}, ctx10 = {0,0,0,0}, ctx11 = {0,0,0,0};
  float se0 = 0.f, se1 = 0.f;

  const float* xw = x + ((size_t)seg * LSEG + sub*1024 + rg*64 + lm) * 128 + lg*8;
  ushort4* q4 = (ushort4*)q_ws;

#define ISSUE(S, IT) { \
    const float* p_ = xw + (size_t)((((IT) >> 2) * 128) + (((IT) & 3) * 16)) * 128; \
    _Pragma("unroll") \
    for (int kk = 0; kk < 4; ++kk) { \
      S[kk][0] = *(const float4*)(p_ + kk*32); \
      S[kk][1] = *(const float4*)(p_ + kk*32 + 4); \
    } }

#define COMPUTE(S, IT) { \
    bf16x8 axf[4]; \
    _Pragma("unroll") for (int kk = 0; kk < 4; ++kk) axf[kk] = cvt8(S[kk][0], S[kk][1]); \
    f32x4 qa0 = {0,0,0,0}, qa1 = {0,0,0,0}; \
    _Pragma("unroll") for (int kk = 0; kk < 4; ++kk) { \
      qa0 = __builtin_amdgcn_mfma_f32_16x16x32_bf16(wq[0][kk], axf[kk], qa0, 0, 0, 0); \
      qa1 = __builtin_amdgcn_mfma_f32_16x16x32_bf16(wq[1][kk], axf[kk], qa1, 0, 0, 0); \
    } \
    { size_t T_ = ((size_t)bid*8 + ((IT) >> 2)) * 64 + (rg*4 + ((IT) & 3)) * 8 + h*2; \
      q4[(T_    ) * 64 + lane] = packu4(qa0); \
      q4[(T_ + 1) * 64 + lane] = packu4(qa1); } \
    f32x4 ka0 = {0,0,0,0}, ka1 = {0,0,0,0}; \
    _Pragma("unroll") for (int kk = 0; kk < 4; ++kk) { \
      ka0 = __builtin_amdgcn_mfma_f32_16x16x32_bf16(axf[kk], wk[0][kk], ka0, 0, 0, 0); \
      ka1 = __builtin_amdgcn_mfma_f32_16x16x32_bf16(axf[kk], wk[1][kk], ka1, 0, 0, 0); \
    } \
    f32x4 va0 = {0,0,0,0}, va1 = {0,0,0,0}; \
    _Pragma("unroll") for (int kk = 0; kk < 4; ++kk) { \
      va0 = __builtin_amdgcn_mfma_f32_16x16x32_bf16(axf[kk], wv[0][kk], va0, 0, 0, 0); \
      va1 = __builtin_amdgcn_mfma_f32_16x16x32_bf16(axf[kk], wv[1][kk], va1, 0, 0, 0); \
    } \
    float e_[8]; \
    _Pragma("unroll") for (int r = 0; r < 4; ++r) e_[r]     = __expf(fmaf(ka0[r], alk, ckv[0])); \
    _Pragma("unroll") for (int r = 0; r < 4; ++r) e_[4 + r] = __expf(fmaf(ka1[r], alk, ckv[1])); \
    se0 += (e_[0] + e_[1]) + (e_[2] + e_[3]); \
    se1 += (e_[4] + e_[5]) + (e_[6] + e_[7]); \
    s16x4 E0 = pack4(e_[0], e_[1], e_[2], e_[3]); \
    s16x4 E1 = pack4(e_[4], e_[5], e_[6], e_[7]); \
    s16x4 V0 = pack4(fmaf(va0[0], alv, cvv[0]), fmaf(va0[1], alv, cvv[0]), \
                     fmaf(va0[2], alv, cvv[0]), fmaf(va0[3], alv, cvv[0])); \
    s16x4 V1 = pack4(fmaf(va1[0], alv, cvv[1]), fmaf(va1[1], alv, cvv[1]), \
                     fmaf(va1[2], alv, cvv[1]), fmaf(va1[3], alv, cvv[1])); \
    ctx00 = __builtin_amdgcn_mfma_f32_16x16x16bf16_1k(E0, V0, ctx00, 0, 0, 0); \
    ctx01 = __builtin_amdgcn_mfma_f32_16x16x16bf16_1k(E0, V1, ctx01, 0, 0, 0); \
    ctx10 = __builtin_amdgcn_mfma_f32_16x16x16bf16_1k(E1, V0, ctx10, 0, 0, 0); \
    ctx11 = __builtin_amdgcn_mfma_f32_16x16x16bf16_1k(E1, V1, ctx11, 0, 0, 0); \
  }

  float4 pa[4][2], pb[4][2];
  ISSUE(pa, 0);
  #pragma unroll 1
  for (int it = 0; it < 32; it += 2) {
    ISSUE(pb, it + 1);
    COMPUTE(pa, it);
    if (it + 2 < 32) ISSUE(pa, it + 2);
    COMPUTE(pb, it + 1);
  }
#undef ISSUE
#undef COMPUTE

  // ---- reduce sum_e: fold lg groups, then rg via LDS
  se0 += __shfl_xor(se0, 16); se0 += __shfl_xor(se0, 32);
  se1 += __shfl_xor(se1, 16); se1 += __shfl_xor(se1, 32);
  if (lane < 16) {
    sume_lds[rg*128 + h*32 + lm]      = se0;
    sume_lds[rg*128 + h*32 + 16 + lm] = se1;
  }
  // ---- reduce ctx across rg (heads are disjoint)
  if (rg == 0) {
    #pragma unroll
    for (int r = 0; r < 4; ++r) {
      cbuf[h*1024 + (lg*4 + r)*32      + lm]      = ctx00[r];
      cbuf[h*1024 + (lg*4 + r)*32      + 16 + lm] = ctx01[r];
      cbuf[h*1024 + (16 + lg*4 + r)*32 + lm]      = ctx10[r];
      cbuf[h*1024 + (16 + lg*4 + r)*32 + 16 + lm] = ctx11[r];
    }
  }
  __syncthreads();
  if (rg == 1) {
    #pragma unroll
    for (int r = 0; r < 4; ++r) {
      cbuf[h*1024 + (lg*4 + r)*32      + lm]      += ctx00[r];
      cbuf[h*1024 + (lg*4 + r)*32      + 16 + lm] += ctx01[r];
      cbuf[h*1024 + (16 + lg*4 + r)*32 + lm]      += ctx10[r];
      cbuf[h*1024 + (16 + lg*4 + r)*32 + 16 + lm] += ctx11[r];
    }
  }
  __syncthreads();
  if (t < 128) sume_p[(size_t)bid*128 + t] = sume_lds[t] + sume_lds[128 + t];
  #pragma unroll
  for (int i = 0; i < 8; ++i) {
    int f = t + i * 512;
    ctx_p[(size_t)bid*4096 + f] = cbuf[f];
  }
}

// ---- finalize: reduce partials, normalize context, fold Wc = blockdiag(ctx) @ W_out (store [oc][qc] bf16)
__global__ __launch_bounds__(512) void k_ctx_final(
    const float* __restrict__ sume_p, const float* __restrict__ ctx_p,
    const float* __restrict__ Wout, unsigned short* __restrict__ WcT)
{
  __shared__ float sse[128];
  __shared__ float sctx[4096];
  __shared__ float sWo[16384];
  const int t = threadIdx.x, b = blockIdx.x;
  if (t < 128) {
    float s = 0.f;
    for (int blk = 0; blk < 32; ++blk) s += sume_p[(size_t)(b * 32 + blk) * 128 + t];
    sse[t] = s;
  }
  float cv[8];
  #pragma unroll
  for (int j = 0; j < 8; ++j) {
    int idx = t + j * 512;
    float s = 0.f;
    for (int blk = 0; blk < 32; ++blk) s += ctx_p[(size_t)(b * 32 + blk) * 4096 + idx];
    cv[j] = s;
  }
  #pragma unroll
  for (int j = 0; j < 32; ++j) sWo[t + j * 512] = Wout[t + j * 512];
  __syncthreads();
  #pragma unroll
  for (int j = 0; j < 8; ++j) {
    int idx = t + j * 512;
    sctx[idx] = cv[j] / sse[idx >> 5];
  }
  __syncthreads();
  const int p = t >> 2, c0 = (t & 3) * 32;
  const int h = p >> 5;
  float acc[32];
  #pragma unroll
  for (int j = 0; j < 32; ++j) acc[j] = 0.f;
  for (int v = 0; v < 32; ++v) {
    float a = sctx[p * 32 + v];
    const float* wr = &sWo[(h * 32 + v) * 128 + c0];
    #pragma unroll
    for (int j = 0; j < 32; ++j) acc[j] += a * wr[j];
  }
  #pragma unroll
  for (int j = 0; j < 32; ++j)
    WcT[((size_t)b * 128 + (c0 + j)) * 128 + p] = f2bf(acc[j]);
}

// ---- q-softmax (transposed frags, cheap shfl) -> out^T = Wc^T @ P^T -> in-place out + GN2 partials
__global__ __launch_bounds__(512) void k_out(
    unsigned short* __restrict__ q_ws, const unsigned short* __restrict__ WcT,
    const float* __restrict__ biasv, const float* __restrict__ alpha,
    float* __restrict__ stats2_p)
{
  __shared__ __attribute__((aligned(16))) unsigned short sWc[128 * 136];   // 34816 B
  __shared__ __attribute__((aligned(16))) unsigned char sO[8][16 * 272];   // 34816 B
  __shared__ float red[16];

  const int t = threadIdx.x, wave = t >> 6, lane = t & 63;
  const int lm = lane & 15, lg = lane >> 4;
  const int bid = blockIdx.x;          // 2048 = 8 seg * 32 sub * 8 ch
  const int seg = bid >> 8;

  // load this wave's 8 q^T tiles (kt = 0..7)
  const ushort4* q4c = (const ushort4*)q_ws;
  ushort4 qt[8];
  #pragma unroll
  for (int kt = 0; kt < 8; ++kt)
    qt[kt] = q4c[((size_t)bid * 64 + wave * 8 + kt) * 64 + lane];

  // stage Wc (pitch 136 ushorts)
  const ushort4* wc4 = (const ushort4*)WcT + (size_t)seg * 4096;
  #pragma unroll
  for (int i = 0; i < 8; ++i) {
    int f = t + i * 512;
    *(ushort4*)&sWc[(f >> 5) * 136 + (f & 31) * 4] = wc4[f];
  }
  const float alq = alpha[seg * 4];
  float4 cq[8];
  #pragma unroll
  for (int kt = 0; kt < 8; ++kt)
    cq[kt] = *(const float4*)&biasv[seg * 384 + kt * 16 + lg * 4];

  __syncthreads();   // all q reads done (in-place overwrite below) + sWc staged

  // softmax over d (32 q-cols per head): 8 in-lane + lg-shfls
  s16x4 p[8];
  #pragma unroll
  for (int h = 0; h < 4; ++h) {
    float a[8];
    #pragma unroll
    for (int nt = 0; nt < 2; ++nt) {
      const unsigned short* qe = (const unsigned short*)&qt[2*h + nt];
      const float* cqe = (const float*)&cq[2*h + nt];
      #pragma unroll
      for (int r = 0; r < 4; ++r)
        a[nt*4 + r] = fmaf(bf2f(qe[r]), alq, cqe[r]);
    }
    float m = a[0];
    #pragma unroll
    for (int i = 1; i < 8; ++i) m = fmaxf(m, a[i]);
    m = fmaxf(m, __shfl_xor(m, 16));
    m = fmaxf(m, __shfl_xor(m, 32));
    float s = 0.f;
    #pragma unroll
    for (int i = 0; i < 8; ++i) { a[i] = __expf(a[i] - m); s += a[i]; }
    s += __shfl_xor(s, 16);
    s += __shfl_xor(s, 32);
    float inv = 1.f / s;
    p[2*h]   = pack4(a[0]*inv, a[1]*inv, a[2]*inv, a[3]*inv);
    p[2*h+1] = pack4(a[4]*inv, a[5]*inv, a[6]*inv, a[7]*inv);
  }

  // out^T[oc][L] = sum_kt Wc^T-frag(A) @ P^T-frag(B)
  float ssum = 0.f, ssq = 0.f;
  unsigned char* so = &sO[wave][0];
  #pragma unroll
  for (int ot = 0; ot < 8; ++ot) {
    f32x4 acc = {0,0,0,0};
    #pragma unroll
    for (int kt = 0; kt < 8; ++kt) {
      s16x4 wf = *(const s16x4*)&sWc[(ot*16 + lm) * 136 + kt*16 + lg*4];
      acc = __builtin_amdgcn_mfma_f32_16x16x16bf16_1k(wf, p[kt], acc, 0, 0, 0);
    }
    #pragma unroll
    for (int r = 0; r < 4; ++r) { ssum += acc[r]; ssq += acc[r] * acc[r]; }
    *(ushort4*)(so + lm * 272 + ot * 32 + lg * 8) = packu4(acc);
  }
  // wave-local transpose staging -> coalesced linear bf16 store (in-place over q region)
  #pragma unroll
  for (int i = 0; i < 4; ++i) {
    int row = i * 4 + (lane >> 4);
    float4 v = *(const float4*)(so + row * 272 + (lane & 15) * 16);
    *(float4*)((char*)q_ws + ((size_t)bid * 128 + wave * 16 + row) * 256 + (lane & 15) * 16) = v;
  }

  #pragma unroll
  for (int o = 1; o < 64; o <<= 1) { ssum += __shfl_xor(ssum, o); ssq += __shfl_xor(ssq, o); }
  if (lane == 0) { red[wave*2] = ssum; red[wave*2+1] = ssq; }
  __syncthreads();
  if (t == 0) {
    float s = 0.f, q = 0.f;
    #pragma unroll
    for (int w = 0; w < 8; ++w) { s += red[w*2]; q += red[w*2+1]; }
    stats2_p[bid*2] = s; stats2_p[bid*2+1] = q;
  }
}

__global__ void k_stats2_final(const float* __restrict__ part, float* __restrict__ stats) {
  int b = blockIdx.x, t = threadIdx.x;  // 256 threads, 256 partials per seg
  float s = part[(b*256 + t)*2], q = part[(b*256 + t)*2 + 1];
  #pragma unroll
  for (int o = 1; o < 64; o <<= 1) { s += __shfl_xor(s, o); q += __shfl_xor(q, o); }
  __shared__ float red[8];
  int wave = t >> 6, lane = t & 63;
  if (lane == 0) { red[wave*2] = s; red[wave*2+1] = q; }
  __syncthreads();
  if (t == 0) {
    float ss = red[0] + red[2] + red[4] + red[6];
    float qq = red[1] + red[3] + red[5] + red[7];
    const float invN = 1.f / 4194304.f;
    float mu = ss * invN;
    float var = qq * invN - mu * mu;
    stats[b*2] = mu;
    stats[b*2+1] = rsqrtf(var + EPS_GN);
  }
}

// ---- GN2 + residual
__global__ __launch_bounds__(256) void k_final(
    const float* __restrict__ x, const unsigned short* __restrict__ out_ws,
    const float* __restrict__ stats2, const float* __restrict__ gn2w, const float* __restrict__ gn2b,
    float* __restrict__ y)
{
  const int t = threadIdx.x;
  const int b = blockIdx.x >> 8, blk = blockIdx.x & 255;
  const float mu = stats2[b*2], rs = stats2[b*2+1];
  const int c4 = t & 31;
  const float4 w4 = *(const float4*)&gn2w[c4*4];
  const float4 g4 = *(const float4*)&gn2b[c4*4];
  const size_t base = (size_t)b * 1048576 + (size_t)blk * 4096;
  const float4* xp = (const float4*)x + base;
  const ushort4* op = (const ushort4*)out_ws + base;
  float4* yp = (float4*)y + base;
  #pragma unroll
  for (int i = 0; i < 16; ++i) {
    int f = t + i * 256;
    float4 xv = xp[f];
    ushort4 ov = op[f];
    float4 r;
    r.x = (bf2f(ov.x) - mu) * rs * w4.x + g4.x + xv.x;
    r.y = (bf2f(ov.y) - mu) * rs * w4.y + g4.y + xv.y;
    r.z = (bf2f(ov.z) - mu) * rs * w4.z + g4.z + xv.z;
    r.w = (bf2f(ov.w) - mu) * rs * w4.w + g4.w + xv.w;
    yp[f] = r;
  }
}

extern "C" void kernel_launch(void* const* d_in, const int* in_sizes, int n_in,
                              void* d_out, int out_size, void* d_ws, size_t ws_size,
                              hipStream_t stream) {
  const float* x    = (const float*)d_in[0];
  const float* gn1w = (const float*)d_in[1];
  const float* gn1b = (const float*)d_in[2];
  const float* Wqkv = (const float*)d_in[3];
  const float* Wout = (const float*)d_in[4];
  const float* gn2w = (const float*)d_in[5];
  const float* gn2b = (const float*)d_in[6];
  float* y = (float*)d_out;
  char* ws = (char*)d_ws;

  float*          stats1p = (float*)(ws + 0);              // 512*2 f32
  float*          stats1  = (float*)(ws + 4096);           // 16 f32
  unsigned short* WT      = (unsigned short*)(ws + 8192);  // 384*128 bf16 = 98304 B
  float*          biasv   = (float*)(ws + 106496);         // 8*384 f32 = 12288 B
  float*          alphav  = (float*)(ws + 118784);         // 8*4 f32
  float*          sume_p  = (float*)(ws + 122880);         // 256*128 f32 = 131072 B
  float*          ctx_p   = (float*)(ws + 253952);         // 256*4096 f32 = 4194304 B
  unsigned short* WcT     = (unsigned short*)(ws + 4448256);  // 8*128*128 bf16 = 262144 B
  float*          stats2p = (float*)(ws + 4710400);        // 2048*2 f32 = 16384 B
  float*          stats2  = (float*)(ws + 4726784);        // 16 f32
  unsigned short* q_ws    = (unsigned short*)(ws + 4849664);  // 8*32768*128 bf16 = 67108864 B

  hipLaunchKernelGGL(k_wcvt,         dim3(192),  dim3(256), 0, stream, Wqkv, gn1w, WT);
  hipLaunchKernelGGL(k_stats1,       dim3(512),  dim3(256), 0, stream, x, stats1p);
  hipLaunchKernelGGL(k_stats1_final, dim3(8),    dim3(64),  0, stream, stats1p, stats1);
  hipLaunchKernelGGL(k_bias,         dim3(8),    dim3(384), 0, stream, Wqkv, gn1w, gn1b, stats1, biasv, alphav);
  hipLaunchKernelGGL(k_qkv,          dim3(256),  dim3(512), 0, stream, x, WT, biasv, alphav, q_ws, sume_p, ctx_p);
  hipLaunchKernelGGL(k_ctx_final,    dim3(8),    dim3(512), 0, stream, sume_p, ctx_p, Wout, WcT);
  hipLaunchKernelGGL(k_out,          dim3(2048), dim3(512), 0, stream, q_ws, WcT, biasv, alphav, stats2p);
  hipLaunchKernelGGL(k_stats2_final, dim3(8),    dim3(256), 0, stream, stats2p, stats2);
  hipLaunchKernelGGL(k_final,        dim3(2048), dim3(256), 0, stream, x, q_ws, stats2, gn2w, gn2b, y);
}

// Round 3
// 211.073 us; speedup vs baseline: 1.1281x; 1.0139x over previous
//
#include <hip/hip_runtime.h>

#define NSEG 8
#define LSEG 32768
#define EPS_GN 1e-5f
#define KSCALE 0.005524271728019903f   // 1/sqrt(32768)
#define QSCALE 0.17677669529663687f    // 1/sqrt(32)

typedef __attribute__((ext_vector_type(4))) float f32x4;
typedef __attribute__((ext_vector_type(8))) __bf16 bf16x8;
typedef __attribute__((ext_vector_type(4))) short s16x4;

#define MFMA32(A, B, C) __builtin_amdgcn_mfma_f32_16x16x32_bf16(A, B, C, 0, 0, 0)
#define MFMA16(A, B, C) __builtin_amdgcn_mfma_f32_16x16x16bf16_1k(A, B, C, 0, 0, 0)

static __device__ __forceinline__ unsigned short f2bf(float f) {
  unsigned int u = __float_as_uint(f);
  u += 0x7fffu + ((u >> 16) & 1u);
  return (unsigned short)(u >> 16);
}
static __device__ __forceinline__ float bf2f(unsigned short s) {
  return __uint_as_float(((unsigned int)s) << 16);
}
static __device__ __forceinline__ s16x4 pack4(float a, float b, float c, float d) {
  union { __bf16 h[4]; s16x4 s; } u;
  u.h[0] = (__bf16)a; u.h[1] = (__bf16)b; u.h[2] = (__bf16)c; u.h[3] = (__bf16)d;
  return u.s;
}
static __device__ __forceinline__ s16x4 as_s16x4(ushort4 v) {
  union { ushort4 u; s16x4 s; } c; c.u = v; return c.s;
}

// ---- fused: GN1 partial stats + x->bf16 copy (blocks 0..511) | W_qkv -> WT bf16 transposed (blocks 512..703)
__global__ __launch_bounds__(256) void k_pre(
    const float* __restrict__ x, float* __restrict__ part, unsigned short* __restrict__ xb,
    const float* __restrict__ W, const float* __restrict__ gn1w, unsigned short* __restrict__ WT)
{
  const int t = threadIdx.x;
  if (blockIdx.x >= 512) {
    int idx = (blockIdx.x - 512) * 256 + t;   // 49152 total
    int n = idx >> 7, ch = idx & 127;
    WT[idx] = f2bf(gn1w[ch] * W[ch * 384 + n]);
    return;
  }
  const int b = blockIdx.x >> 6, p = blockIdx.x & 63;
  const float4* xp = (const float4*)x + (size_t)b * 1048576 + (size_t)p * 16384;
  ushort4* xo = (ushort4*)xb + (size_t)b * 1048576 + (size_t)p * 16384;
  float s = 0.f, q = 0.f;
  for (int i = 0; i < 64; ++i) {
    float4 v = xp[t + i * 256];
    s += v.x + v.y + v.z + v.w;
    q += v.x*v.x + v.y*v.y + v.z*v.z + v.w*v.w;
    xo[t + i * 256] = make_ushort4(f2bf(v.x), f2bf(v.y), f2bf(v.z), f2bf(v.w));
  }
  #pragma unroll
  for (int o = 1; o < 64; o <<= 1) { s += __shfl_xor(s, o); q += __shfl_xor(q, o); }
  __shared__ float red[8];
  int wave = t >> 6, lane = t & 63;
  if (lane == 0) { red[wave*2] = s; red[wave*2+1] = q; }
  __syncthreads();
  if (t == 0) {
    part[blockIdx.x*2]   = red[0] + red[2] + red[4] + red[6];
    part[blockIdx.x*2+1] = red[1] + red[3] + red[5] + red[7];
  }
}

// ---- per-segment: finalize stats1 + folded GN1 bias through W_qkv + alpha scales
__global__ void k_bias(const float* __restrict__ Wqkv, const float* __restrict__ gn1w,
                       const float* __restrict__ gn1b, const float* __restrict__ part,
                       float* __restrict__ biasv, float* __restrict__ alpha) {
  const int seg = blockIdx.x, t = threadIdx.x;  // 384 threads
  __shared__ float sm[2];
  if (t < 64) {
    float s = part[(seg*64 + t)*2], q = part[(seg*64 + t)*2 + 1];
    #pragma unroll
    for (int o = 1; o < 64; o <<= 1) { s += __shfl_xor(s, o); q += __shfl_xor(q, o); }
    if (t == 0) {
      const float invN = 1.f / 4194304.f;
      float mu = s * invN;
      float var = q * invN - mu * mu;
      sm[0] = mu; sm[1] = rsqrtf(var + EPS_GN);
    }
  }
  __syncthreads();
  const float mu = sm[0], rs = sm[1];
  float s = 0.f;
  for (int ch = 0; ch < 128; ++ch)
    s += (gn1b[ch] - mu * rs * gn1w[ch]) * Wqkv[ch * 384 + t];
  float scale = (t < 128) ? QSCALE : ((t < 256) ? KSCALE : 1.f);
  biasv[seg*384 + t] = s * scale;
  if (t == 0) {
    alpha[seg*4]   = rs * QSCALE;
    alpha[seg*4+1] = rs * KSCALE;
    alpha[seg*4+2] = rs;
  }
}

// ---- fused GEMM: xb(bf16 frags from global) @ W(register-resident) -> q-softmax -> P^T store;
//      exp(k)->sum_e; ctx += E^T@V.  256 thr = 4 waves = 4 heads; NO LDS, NO barriers.
__global__ __launch_bounds__(256, 2) void k_qkv(
    const unsigned short* __restrict__ xb, const unsigned short* __restrict__ WT,
    const float* __restrict__ biasv, const float* __restrict__ alpha,
    unsigned short* __restrict__ q_ws, float* __restrict__ sume_p, float* __restrict__ ctx_p)
{
  const int t = threadIdx.x;
  const int h = t >> 6, lane = t & 63;
  const int lm = lane & 15, lg = lane >> 4;
  const int bid = blockIdx.x;               // 512 = 8 seg * 64 sub
  const int seg = bid >> 6, sub = bid & 63;

  // register-resident W fragments [nt][kk] (dual-use A/B layout)
  bf16x8 wq[2][4], wk[2][4], wv[2][4];
  #pragma unroll
  for (int nt = 0; nt < 2; ++nt)
    #pragma unroll
    for (int kk = 0; kk < 4; ++kk) {
      int row = h*32 + nt*16 + lm;
      wq[nt][kk] = *(const bf16x8*)&WT[(row      ) * 128 + kk*32 + lg*8];
      wk[nt][kk] = *(const bf16x8*)&WT[(row + 128) * 128 + kk*32 + lg*8];
      wv[nt][kk] = *(const bf16x8*)&WT[(row + 256) * 128 + kk*32 + lg*8];
    }
  const float alq = alpha[seg*4], alk = alpha[seg*4 + 1], alv = alpha[seg*4 + 2];
  const float4 cq0 = *(const float4*)&biasv[seg*384 + h*32 +      lg*4];
  const float4 cq1 = *(const float4*)&biasv[seg*384 + h*32 + 16 + lg*4];
  const float ck0 = biasv[seg*384 + 128 + h*32 + lm];
  const float ck1 = biasv[seg*384 + 128 + h*32 + 16 + lm];
  const float cv0 = biasv[seg*384 + 256 + h*32 + lm];
  const float cv1 = biasv[seg*384 + 256 + h*32 + 16 + lm];

  f32x4 ctx00 = {0,0,0,0}, ctx01 = {0,0,0,0}, ctx10 = {0,0,0,0}, ctx11 = {0,0,0,0};
  float se0 = 0.f, se1 = 0.f;

  const unsigned short* xw = xb + (size_t)(seg * LSEG + sub*512 + lm) * 128 + lg*8;
  ushort4* q4 = (ushort4*)q_ws;

#define ISSUE(S, IT) { \
    const unsigned short* p_ = xw + (size_t)((((IT) >> 3) * 128) + (((IT) & 7) * 16)) * 128; \
    S[0] = *(const bf16x8*)(p_);      \
    S[1] = *(const bf16x8*)(p_ + 32); \
    S[2] = *(const bf16x8*)(p_ + 64); \
    S[3] = *(const bf16x8*)(p_ + 96); }

#define COMPUTE(S, IT) { \
    f32x4 qa0 = {0,0,0,0}, qa1 = {0,0,0,0}; \
    _Pragma("unroll") for (int kk = 0; kk < 4; ++kk) { \
      qa0 = MFMA32(wq[0][kk], S[kk], qa0); \
      qa1 = MFMA32(wq[1][kk], S[kk], qa1); \
    } \
    float a_[8]; \
    _Pragma("unroll") for (int r = 0; r < 4; ++r) { \
      a_[r]     = fmaf(qa0[r], alq, ((const float*)&cq0)[r]); \
      a_[4 + r] = fmaf(qa1[r], alq, ((const float*)&cq1)[r]); \
    } \
    float m_ = a_[0]; \
    _Pragma("unroll") for (int i = 1; i < 8; ++i) m_ = fmaxf(m_, a_[i]); \
    m_ = fmaxf(m_, __shfl_xor(m_, 16)); \
    m_ = fmaxf(m_, __shfl_xor(m_, 32)); \
    float s_ = 0.f; \
    _Pragma("unroll") for (int i = 0; i < 8; ++i) { a_[i] = __expf(a_[i] - m_); s_ += a_[i]; } \
    s_ += __shfl_xor(s_, 16); \
    s_ += __shfl_xor(s_, 32); \
    float inv_ = 1.f / s_; \
    { size_t T_ = ((size_t)(bid*4 + ((IT) >> 3))) * 64 + ((IT) & 7) * 8 + h*2; \
      q4[T_*64 + lane]     = make_ushort4(f2bf(a_[0]*inv_), f2bf(a_[1]*inv_), f2bf(a_[2]*inv_), f2bf(a_[3]*inv_)); \
      q4[(T_+1)*64 + lane] = make_ushort4(f2bf(a_[4]*inv_), f2bf(a_[5]*inv_), f2bf(a_[6]*inv_), f2bf(a_[7]*inv_)); } \
    f32x4 ka0 = {0,0,0,0}, ka1 = {0,0,0,0}, va0 = {0,0,0,0}, va1 = {0,0,0,0}; \
    _Pragma("unroll") for (int kk = 0; kk < 4; ++kk) { \
      ka0 = MFMA32(S[kk], wk[0][kk], ka0); \
      ka1 = MFMA32(S[kk], wk[1][kk], ka1); \
    } \
    _Pragma("unroll") for (int kk = 0; kk < 4; ++kk) { \
      va0 = MFMA32(S[kk], wv[0][kk], va0); \
      va1 = MFMA32(S[kk], wv[1][kk], va1); \
    } \
    float e_[8]; \
    _Pragma("unroll") for (int r = 0; r < 4; ++r) { \
      e_[r]     = __expf(fmaf(ka0[r], alk, ck0)); \
      e_[4 + r] = __expf(fmaf(ka1[r], alk, ck1)); \
    } \
    se0 += (e_[0] + e_[1]) + (e_[2] + e_[3]); \
    se1 += (e_[4] + e_[5]) + (e_[6] + e_[7]); \
    s16x4 E0 = pack4(e_[0], e_[1], e_[2], e_[3]); \
    s16x4 E1 = pack4(e_[4], e_[5], e_[6], e_[7]); \
    s16x4 V0 = pack4(fmaf(va0[0], alv, cv0), fmaf(va0[1], alv, cv0), \
                     fmaf(va0[2], alv, cv0), fmaf(va0[3], alv, cv0)); \
    s16x4 V1 = pack4(fmaf(va1[0], alv, cv1), fmaf(va1[1], alv, cv1), \
                     fmaf(va1[2], alv, cv1), fmaf(va1[3], alv, cv1)); \
    ctx00 = MFMA16(E0, V0, ctx00); \
    ctx01 = MFMA16(E0, V1, ctx01); \
    ctx10 = MFMA16(E1, V0, ctx10); \
    ctx11 = MFMA16(E1, V1, ctx11); }

  bf16x8 sA[4], sB[4], sC[4], sD[4];
  ISSUE(sA, 0);
  ISSUE(sB, 1);
  #pragma unroll 1
  for (int it = 0; it < 32; it += 4) {
    ISSUE(sC, it + 2);
    COMPUTE(sA, it);
    ISSUE(sD, it + 3);
    COMPUTE(sB, it + 1);
    if (it + 4 < 32) ISSUE(sA, it + 4);
    COMPUTE(sC, it + 2);
    if (it + 5 < 32) ISSUE(sB, it + 5);
    COMPUTE(sD, it + 3);
  }
#undef ISSUE
#undef COMPUTE

  // ---- per-wave epilogue (heads disjoint): sum_e over points, ctx quadrants
  se0 += __shfl_xor(se0, 16); se0 += __shfl_xor(se0, 32);
  se1 += __shfl_xor(se1, 16); se1 += __shfl_xor(se1, 32);
  if (lane < 16) {
    sume_p[(size_t)bid*128 + h*32 + lm]      = se0;
    sume_p[(size_t)bid*128 + h*32 + 16 + lm] = se1;
  }
  float* cp = ctx_p + (size_t)bid*4096 + h*1024;
  #pragma unroll
  for (int r = 0; r < 4; ++r) {
    cp[(lg*4 + r)*32      + lm]      = ctx00[r];
    cp[(lg*4 + r)*32      + 16 + lm] = ctx01[r];
    cp[(16 + lg*4 + r)*32 + lm]      = ctx10[r];
    cp[(16 + lg*4 + r)*32 + 16 + lm] = ctx11[r];
  }
}

// ---- finalize: reduce partials, normalize context, fold Wc = blockdiag(ctx) @ W_out (store [oc][qc] bf16)
__global__ __launch_bounds__(512) void k_ctx_final(
    const float* __restrict__ sume_p, const float* __restrict__ ctx_p,
    const float* __restrict__ Wout, unsigned short* __restrict__ WcT)
{
  __shared__ float sse[128];
  __shared__ float sctx[4096];
  __shared__ float sWo[16384];
  const int t = threadIdx.x, b = blockIdx.x;
  if (t < 128) {
    float s = 0.f;
    for (int blk = 0; blk < 64; ++blk) s += sume_p[(size_t)(b * 64 + blk) * 128 + t];
    sse[t] = s;
  }
  float cv[8];
  #pragma unroll
  for (int j = 0; j < 8; ++j) {
    int idx = t + j * 512;
    float s = 0.f;
    for (int blk = 0; blk < 64; ++blk) s += ctx_p[(size_t)(b * 64 + blk) * 4096 + idx];
    cv[j] = s;
  }
  #pragma unroll
  for (int j = 0; j < 32; ++j) sWo[t + j * 512] = Wout[t + j * 512];
  __syncthreads();
  #pragma unroll
  for (int j = 0; j < 8; ++j) {
    int idx = t + j * 512;
    sctx[idx] = cv[j] / sse[idx >> 5];
  }
  __syncthreads();
  const int p = t >> 2, c0 = (t & 3) * 32;
  const int h = p >> 5;
  float acc[32];
  #pragma unroll
  for (int j = 0; j < 32; ++j) acc[j] = 0.f;
  for (int v = 0; v < 32; ++v) {
    float a = sctx[p * 32 + v];
    const float* wr = &sWo[(h * 32 + v) * 128 + c0];
    #pragma unroll
    for (int j = 0; j < 32; ++j) acc[j] += a * wr[j];
  }
  #pragma unroll
  for (int j = 0; j < 32; ++j)
    WcT[((size_t)b * 128 + (c0 + j)) * 128 + p] = f2bf(acc[j]);
}

// ---- pure GEMM: out^T = Wc^T(A) @ P^T(B) -> transpose-store in-place over P + GN2 partials
__global__ __launch_bounds__(512) void k_out(
    unsigned short* __restrict__ q_ws, const unsigned short* __restrict__ WcT,
    float* __restrict__ stats2_p)
{
  __shared__ __attribute__((aligned(16))) unsigned short sWc[128 * 136];   // 34816 B
  __shared__ __attribute__((aligned(16))) unsigned char sO[8][16 * 272];   // 34816 B
  __shared__ float red[16];

  const int t = threadIdx.x, wave = t >> 6, lane = t & 63;
  const int lm = lane & 15, lg = lane >> 4;
  const int bid = blockIdx.x;          // 2048 = 8 seg * 256 point-groups
  const int seg = bid >> 8;

  // load this wave's 8 P^T tiles (kt = h*2+nt)
  const ushort4* q4c = (const ushort4*)q_ws;
  s16x4 p[8];
  #pragma unroll
  for (int kt = 0; kt < 8; ++kt)
    p[kt] = as_s16x4(q4c[((size_t)bid * 64 + wave * 8 + kt) * 64 + lane]);

  // stage Wc (pitch 136 ushorts)
  const ushort4* wc4 = (const ushort4*)WcT + (size_t)seg * 4096;
  #pragma unroll
  for (int i = 0; i < 8; ++i) {
    int f = t + i * 512;
    *(ushort4*)&sWc[(f >> 5) * 136 + (f & 31) * 4] = wc4[f];
  }
  __syncthreads();

  float ssum = 0.f, ssq = 0.f;
  unsigned char* so = &sO[wave][0];
  #pragma unroll
  for (int ot = 0; ot < 8; ++ot) {
    f32x4 acc = {0,0,0,0};
    #pragma unroll
    for (int kt = 0; kt < 8; ++kt) {
      s16x4 wf = *(const s16x4*)&sWc[(ot*16 + lm) * 136 + kt*16 + lg*4];
      acc = MFMA16(wf, p[kt], acc);
    }
    #pragma unroll
    for (int r = 0; r < 4; ++r) { ssum += acc[r]; ssq += acc[r] * acc[r]; }
    *(ushort4*)(so + lm * 272 + ot * 32 + lg * 8) =
        make_ushort4(f2bf(acc[0]), f2bf(acc[1]), f2bf(acc[2]), f2bf(acc[3]));
  }
  // wave-local transpose staging -> coalesced linear bf16 store (in-place over this wave's P bytes)
  #pragma unroll
  for (int i = 0; i < 4; ++i) {
    int row = i * 4 + (lane >> 4);
    float4 v = *(const float4*)(so + row * 272 + (lane & 15) * 16);
    *(float4*)((char*)q_ws + ((size_t)bid * 128 + wave * 16 + row) * 256 + (lane & 15) * 16) = v;
  }

  #pragma unroll
  for (int o = 1; o < 64; o <<= 1) { ssum += __shfl_xor(ssum, o); ssq += __shfl_xor(ssq, o); }
  if (lane == 0) { red[wave*2] = ssum; red[wave*2+1] = ssq; }
  __syncthreads();
  if (t == 0) {
    float s = 0.f, q = 0.f;
    #pragma unroll
    for (int w = 0; w < 8; ++w) { s += red[w*2]; q += red[w*2+1]; }
    stats2_p[bid*2] = s; stats2_p[bid*2+1] = q;
  }
}

// ---- GN2 (stats folded in) + residual (bf16 x)
__global__ __launch_bounds__(256) void k_final(
    const unsigned short* __restrict__ xb, const unsigned short* __restrict__ out_ws,
    const float* __restrict__ stats2_p, const float* __restrict__ gn2w, const float* __restrict__ gn2b,
    float* __restrict__ y)
{
  __shared__ float red[8];
  __shared__ float sm[2];
  const int t = threadIdx.x;
  const int b = blockIdx.x >> 8, blk = blockIdx.x & 255;
  {
    float s = stats2_p[(b*256 + t)*2], q = stats2_p[(b*256 + t)*2 + 1];
    #pragma unroll
    for (int o = 1; o < 64; o <<= 1) { s += __shfl_xor(s, o); q += __shfl_xor(q, o); }
    int wave = t >> 6, lane = t & 63;
    if (lane == 0) { red[wave*2] = s; red[wave*2+1] = q; }
    __syncthreads();
    if (t == 0) {
      float ss = red[0] + red[2] + red[4] + red[6];
      float qq = red[1] + red[3] + red[5] + red[7];
      const float invN = 1.f / 4194304.f;
      float mu = ss * invN;
      float var = qq * invN - mu * mu;
      sm[0] = mu; sm[1] = rsqrtf(var + EPS_GN);
    }
    __syncthreads();
  }
  const float mu = sm[0], rs = sm[1];
  const int c4 = t & 31;
  const float4 w4 = *(const float4*)&gn2w[c4*4];
  const float4 g4 = *(const float4*)&gn2b[c4*4];
  const size_t base = (size_t)b * 1048576 + (size_t)blk * 4096;
  const ushort4* xp = (const ushort4*)xb + base;
  const ushort4* op = (const ushort4*)out_ws + base;
  float4* yp = (float4*)y + base;
  #pragma unroll
  for (int i = 0; i < 16; ++i) {
    int f = t + i * 256;
    ushort4 xv = xp[f];
    ushort4 ov = op[f];
    float4 r;
    r.x = (bf2f(ov.x) - mu) * rs * w4.x + g4.x + bf2f(xv.x);
    r.y = (bf2f(ov.y) - mu) * rs * w4.y + g4.y + bf2f(xv.y);
    r.z = (bf2f(ov.z) - mu) * rs * w4.z + g4.z + bf2f(xv.z);
    r.w = (bf2f(ov.w) - mu) * rs * w4.w + g4.w + bf2f(xv.w);
    yp[f] = r;
  }
}

extern "C" void kernel_launch(void* const* d_in, const int* in_sizes, int n_in,
                              void* d_out, int out_size, void* d_ws, size_t ws_size,
                              hipStream_t stream) {
  const float* x    = (const float*)d_in[0];
  const float* gn1w = (const float*)d_in[1];
  const float* gn1b = (const float*)d_in[2];
  const float* Wqkv = (const float*)d_in[3];
  const float* Wout = (const float*)d_in[4];
  const float* gn2w = (const float*)d_in[5];
  const float* gn2b = (const float*)d_in[6];
  float* y = (float*)d_out;
  char* ws = (char*)d_ws;

  float*          part    = (float*)(ws + 0);              // 512*2 f32 = 4096 B
  unsigned short* WT      = (unsigned short*)(ws + 8192);  // 384*128 bf16 = 98304 B
  float*          biasv   = (float*)(ws + 106496);         // 8*384 f32 = 12288 B
  float*          alphav  = (float*)(ws + 118784);         // 8*4 f32
  float*          sume_p  = (float*)(ws + 122880);         // 512*128 f32 = 262144 B
  float*          ctx_p   = (float*)(ws + 385024);         // 512*4096 f32 = 8388608 B
  unsigned short* WcT     = (unsigned short*)(ws + 8773632);  // 8*128*128 bf16 = 262144 B
  float*          stats2p = (float*)(ws + 9035776);        // 2048*2 f32 = 16384 B
  unsigned short* xb      = (unsigned short*)(ws + 9052160);  // 8*32768*128 bf16 = 67108864 B
  unsigned short* q_ws    = (unsigned short*)(ws + 76161024); // 8*32768*128 bf16 = 67108864 B

  hipLaunchKernelGGL(k_pre,       dim3(704),  dim3(256), 0, stream, x, part, xb, Wqkv, gn1w, WT);
  hipLaunchKernelGGL(k_bias,      dim3(8),    dim3(384), 0, stream, Wqkv, gn1w, gn1b, part, biasv, alphav);
  hipLaunchKernelGGL(k_qkv,       dim3(512),  dim3(256), 0, stream, xb, WT, biasv, alphav, q_ws, sume_p, ctx_p);
  hipLaunchKernelGGL(k_ctx_final, dim3(8),    dim3(512), 0, stream, sume_p, ctx_p, Wout, WcT);
  hipLaunchKernelGGL(k_out,       dim3(2048), dim3(512), 0, stream, q_ws, WcT, stats2p);
  hipLaunchKernelGGL(k_final,     dim3(2048), dim3(256), 0, stream, xb, q_ws, stats2p, gn2w, gn2b, y);
}